// Round 4
// baseline (54.447 us; speedup 1.0000x reference)
//
#include <hip/hip_runtime.h>

#define ROWF 84            // floats per output row (80 cls + 4 reg)
#define KSLOT 8            // per-thread green-label register slots
#define SENT 0xFFFFFFFFu

// One block = 256 consecutive points (4 waves) of one image. Level cumsums
// (16384,20480,21504,21760,21824) are all 256-aligned -> every block is
// level-uniform (last block: 64 valid points).
//  entry  : issue 20 own-row zero float4 stores (fire-and-forget)
//  phase 0: cooperative gt preload + size classification (1 gt/thread);
//           wave 0 ballot-compacts size-relevant gts (ascending g)
//  phase 2: branchless min-score scan over ALL gts (argmin fallback)
//  vmcnt(0) (drain long since overlapped)
//  phase 3: compacted gts: hit test; gray->bitmask; green->register slot
//           max-merge (static-indexed, stays in VGPRs) or rare atomic spill
//  phase 4: patch stores to DISTINCT addresses of own row (slots skip
//           gray labels), gray -1 stores, reg float4 -> no ordering needed.
__global__ __launch_bounds__(256, 2) void lfd_assign_kernel(
    const float* __restrict__ gt_bboxes,   // (B,G,4) x0,y0,w,h
    const int*   __restrict__ gt_labels,   // (B,G)
    const float* __restrict__ points,      // (P,2)
    const float* __restrict__ reg_ranges,  // (P,2)
    const float* __restrict__ gray_ranges, // (P,2)
    const float* __restrict__ strides,     // (P,)
    float* __restrict__ out,               // (B,P,84)
    int G, int P)
{
    extern __shared__ float lds[];
    float4*   boxA  = (float4*)lds;                        // [G] x0,y0,x1m1,y1m1
    float2*   ctr   = (float2*)(boxA + G);                 // [G] cx,cy (16B-aligned base)
    unsigned* clist = (unsigned*)(ctr + ((G + 1) & ~1));   // [G]
    unsigned* flags = clist + G;                           // [128]
    int*      s_ncomp = (int*)(flags + 128);

    const int tid = threadIdx.x;
    const int b   = blockIdx.y;
    const int p   = blockIdx.x * 256 + tid;
    const bool active = (p < P);
    const int  pc = active ? p : (P - 1);   // clamped (block is level-uniform)

    // --- entry: own-row zero stores, issued before anything else ---
    float* myout = out + ((size_t)b * P + p) * ROWF;   // 336B stride, 16B-aligned
    if (active) {
        const float4 z = make_float4(0.f, 0.f, 0.f, 0.f);
        float4* r4 = (float4*)myout;
#pragma unroll
        for (int k = 0; k < 20; ++k) r4[k] = z;        // classes 0..79; reg word stored later
    }

    // --- per-point (block-uniform level) constants ---
    const float px  = points[pc * 2 + 0];
    const float py  = points[pc * 2 + 1];
    const float lo  = reg_ranges[pc * 2 + 0];
    const float up  = reg_ranges[pc * 2 + 1];
    const float glo = gray_ranges[pc * 2 + 0];
    const float gup = gray_ranges[pc * 2 + 1];
    const float inv_half = 2.0f / strides[pc];  // strides pow2 -> exact
    const float inv_up   = 1.0f / up;

    // --- phase 0: cooperative preload + classify (1 gt per thread) ---
    if (tid < 128) {
        unsigned f = SENT;
        if (tid < G) {
            const float4 bb = *(const float4*)(gt_bboxes + ((size_t)b * G + tid) * 4);
            boxA[tid] = make_float4(bb.x, bb.y, bb.x + bb.z - 1.0f, bb.y + bb.w - 1.0f);
            ctr[tid]  = make_float2(bb.x + 0.5f * bb.z, bb.y + 0.5f * bb.w);
            const float larger = fmaxf(bb.z, bb.w);
            const int lab = gt_labels[b * G + tid];
            const bool green = (lo <= larger) && (larger <= up);
            const bool gray  = ((glo <= larger) && (larger < lo)) ||
                               ((up < larger) && (larger <= gup));
            if (green || gray)
                f = (unsigned)tid | ((unsigned)lab << 8) | (gray ? 0x80000000u : 0u);
        }
        flags[tid] = f;
    }
    __syncthreads();

    // --- wave 0 compacts (ascending-g order -> stable-sort tie semantics) ---
    if (tid < 64) {
        const unsigned f0 = flags[tid], f1 = flags[tid + 64];
        const bool i0 = (f0 != SENT), i1 = (f1 != SENT);
        const unsigned long long m0 = __ballot(i0);
        const unsigned long long m1 = __ballot(i1);
        const unsigned long long below = (1ull << tid) - 1ull;
        const int c0 = __popcll(m0);
        if (i0) clist[__popcll(m0 & below)] = f0;
        if (i1) clist[c0 + __popcll(m1 & below)] = f1;
        if (tid == 0) *s_ncomp = c0 + __popcll(m1);
    }
    __syncthreads();
    const int ncomp = *s_ncomp;

    // --- phase 2: branchless min-score scan over ALL gts (2 per b128) ---
    const float4* ctr2 = (const float4*)ctr;
    float min_score = 1e30f; int min_g = 0;
    int g = 0;
#pragma unroll 4
    for (; g + 1 < G; g += 2) {
        const float4 c = ctr2[g >> 1];
        const float s0 = rsqrtf(fmaxf(fabsf(px - c.x) * inv_half, 1.0f) *
                                fmaxf(fabsf(py - c.y) * inv_half, 1.0f));
        const float s1 = rsqrtf(fmaxf(fabsf(px - c.z) * inv_half, 1.0f) *
                                fmaxf(fabsf(py - c.w) * inv_half, 1.0f));
        if (s0 < min_score) { min_score = s0; min_g = g; }
        if (s1 < min_score) { min_score = s1; min_g = g + 1; }
    }
    if (g < G) {
        const float2 c = ctr[g];
        const float s0 = rsqrtf(fmaxf(fabsf(px - c.x) * inv_half, 1.0f) *
                                fmaxf(fabsf(py - c.y) * inv_half, 1.0f));
        if (s0 < min_score) { min_score = s0; min_g = g; }
    }

    // zeros (and all loads) complete; drain overlapped with phases 0+2
    asm volatile("s_waitcnt vmcnt(0)" ::: "memory");

    // --- phase 3: compacted gts: hit test, slot merge / gray mask ---
    int   slab[KSLOT];
    float sval[KSLOT];
#pragma unroll
    for (int j = 0; j < KSLOT; ++j) { slab[j] = -1; sval[j] = 0.f; }
    int cnt = 0; bool spill = false;
    unsigned gm0 = 0u, gm1 = 0u, gm2 = 0u;
    float best_score = 0.f; int best_g = 0;

    for (int i = 0; i < ncomp; ++i) {
        const unsigned e = clist[i];
        const int gg = (int)(e & 0xFFu);
        const float4 A = boxA[gg];
        const float d1 = px - A.x, d2 = py - A.y, d3 = A.z - px, d4 = A.w - py;
        if (active && fminf(fminf(d1, d2), fminf(d3, d4)) >= 0.0f) {
            const int label = (int)((e >> 8) & 0x7Fu);
            if (e & 0x80000000u) {              // gray
                if (label < 32)      gm0 |= 1u << label;
                else if (label < 64) gm1 |= 1u << (label - 32);
                else                 gm2 |= 1u << (label - 64);
            } else {                             // green
                const float2 c = ctr[gg];
                const float s = rsqrtf(fmaxf(fabsf(px - c.x) * inv_half, 1.0f) *
                                       fmaxf(fabsf(py - c.y) * inv_half, 1.0f));
                bool placed = false;
#pragma unroll
                for (int j = 0; j < KSLOT; ++j)
                    if (slab[j] == label) { sval[j] = fmaxf(sval[j], s); placed = true; }
                if (!placed) {
                    if (cnt < KSLOT) {
#pragma unroll
                        for (int j = 0; j < KSLOT; ++j)
                            if (cnt == j) { slab[j] = label; sval[j] = s; }
                        ++cnt;
                    } else {
                        spill = true;           // rare (L3 only): zeros already visible
                        atomicMax((int*)(myout + label), __float_as_int(s));
                    }
                }
                if (s > best_score) { best_score = s; best_g = gg; }
            }
        }
    }
    if (__any(spill))   // spill atomics must land before gray -1 overrides
        asm volatile("s_waitcnt vmcnt(0)" ::: "memory");

    // --- phase 4: patch stores (all distinct addresses within own row) ---
    if (active) {
#pragma unroll
        for (int j = 0; j < KSLOT; ++j) {
            if (j < cnt) {
                const int L = slab[j];
                const unsigned gmask = (L < 32) ? gm0 : ((L < 64) ? gm1 : gm2);
                if (!((gmask >> (L & 31)) & 1u))   // gray wins -> skip green store
                    myout[L] = sval[j];
            }
        }
        unsigned t;
        t = gm0; while (t) { const int c = __ffs(t) - 1; myout[c]      = -1.0f; t &= t - 1u; }
        t = gm1; while (t) { const int c = __ffs(t) - 1; myout[32 + c] = -1.0f; t &= t - 1u; }
        t = gm2; while (t) { const int c = __ffs(t) - 1; myout[64 + c] = -1.0f; t &= t - 1u; }

        const int sel = (best_score > 0.f) ? best_g : min_g;
        const float4 A = boxA[sel];
        *(float4*)(myout + 80) = make_float4((px - A.x) * inv_up, (py - A.y) * inv_up,
                                             (A.z - px) * inv_up, (A.w - py) * inv_up);
    }
}

extern "C" void kernel_launch(void* const* d_in, const int* in_sizes, int n_in,
                              void* d_out, int out_size, void* d_ws, size_t ws_size,
                              hipStream_t stream) {
    const float* gt_bboxes   = (const float*)d_in[0];
    const int*   gt_labels   = (const int*)d_in[1];
    const float* points      = (const float*)d_in[2];
    const float* reg_ranges  = (const float*)d_in[3];
    const float* gray_ranges = (const float*)d_in[4];
    const float* strides     = (const float*)d_in[5];
    float* out = (float*)d_out;

    const int P = in_sizes[5];            // strides has P elements
    const int B = out_size / (P * ROWF);  // out is (B,P,84)
    const int G = in_sizes[1] / B;        // gt_labels is (B,G)  (G<=128 assumed)

    dim3 grid((P + 255) / 256, B);
    dim3 block(256);
    const size_t shmem = (size_t)G * sizeof(float4)               // boxA
                       + (size_t)((G + 1) & ~1) * sizeof(float2)  // ctr
                       + (size_t)G * sizeof(unsigned)             // clist
                       + 128 * sizeof(unsigned)                   // flags
                       + sizeof(int);                             // ncomp
    lfd_assign_kernel<<<grid, block, shmem, stream>>>(
        gt_bboxes, gt_labels, points, reg_ranges, gray_ranges, strides, out, G, P);
}

// Round 5
// 41.978 us; speedup vs baseline: 1.2970x; 1.2970x over previous
//
#include <hip/hip_runtime.h>

#define ROWF 84        // floats per output row (80 cls + 4 reg)

// ---------------- Kernel A: grid-stride coalesced zero fill ----------------
// Same pattern as the runtime's fillBufferAligned (measured 6.5 TB/s here).
__global__ __launch_bounds__(256) void lfd_zero_kernel(float4* __restrict__ dst, int n4) {
    const int stride = gridDim.x * blockDim.x;
    const float4 z = make_float4(0.f, 0.f, 0.f, 0.f);
    for (int i = blockIdx.x * blockDim.x + threadIdx.x; i < n4; i += stride)
        dst[i] = z;
}

// ---------------- Kernel B: compute + sparse patches ----------------
// One block = one wave = 64 consecutive points of one image (levels are
// 64-aligned -> wave is level-uniform; P = 341*64 exactly, no tail).
// Runs AFTER the zero fill (stream order). Per-point patches touch only the
// thread's own row: green -> atomicMax over zeros (commutative, determin-
// istic), gray -> -1 stores after a cheap vmcnt fence, reg -> one float4.
// No bulk stores in this kernel => no wave ever waits on the 57 MB backlog.
__global__ __launch_bounds__(64) void lfd_patch_kernel(
    const float* __restrict__ gt_bboxes,   // (B,G,4) x0,y0,w,h
    const int*   __restrict__ gt_labels,   // (B,G)
    const float* __restrict__ points,      // (P,2)
    const float* __restrict__ reg_ranges,  // (P,2)
    const float* __restrict__ gray_ranges, // (P,2)
    const float* __restrict__ strides,     // (P,)
    float* __restrict__ out,               // (B,P,84)
    int G, int P)
{
    extern __shared__ float lds[];
    float4*   boxA  = (float4*)lds;                      // [G] x0,y0,x1m1,y1m1
    float2*   ctr   = (float2*)(boxA + G);               // [G] cx,cy
    unsigned* clist = (unsigned*)(ctr + ((G + 1) & ~1)); // [G] compacted

    const int tid = threadIdx.x;
    const int b   = blockIdx.y;
    const int p   = blockIdx.x * 64 + tid;

    // --- per-point (wave-uniform level) constants ---
    const float px  = points[p * 2 + 0];
    const float py  = points[p * 2 + 1];
    const float lo  = reg_ranges[p * 2 + 0];
    const float up  = reg_ranges[p * 2 + 1];
    const float glo = gray_ranges[p * 2 + 0];
    const float gup = gray_ranges[p * 2 + 1];
    const float inv_half = 2.0f / strides[p];  // strides pow2 -> exact
    const float inv_up   = 1.0f / up;

    // --- preload gts (slots g=tid, g=tid+64), classify size-relevance ---
    bool i0 = false, gray0 = false, i1 = false, gray1 = false;
    int  lab0 = 0, lab1 = 0;
    {
        int g = tid;
        if (g < G) {
            const float4 bb = *(const float4*)(gt_bboxes + (size_t)(b * G + g) * 4);
            boxA[g] = make_float4(bb.x, bb.y, bb.x + bb.z - 1.0f, bb.y + bb.w - 1.0f);
            ctr[g]  = make_float2(bb.x + 0.5f * bb.z, bb.y + 0.5f * bb.w);
            const float larger = fmaxf(bb.z, bb.w);
            lab0 = gt_labels[b * G + g];
            const bool green = (lo <= larger) && (larger <= up);
            gray0 = ((glo <= larger) && (larger < lo)) || ((up < larger) && (larger <= gup));
            i0 = green || gray0;
        }
        g = tid + 64;
        if (g < G) {
            const float4 bb = *(const float4*)(gt_bboxes + (size_t)(b * G + g) * 4);
            boxA[g] = make_float4(bb.x, bb.y, bb.x + bb.z - 1.0f, bb.y + bb.w - 1.0f);
            ctr[g]  = make_float2(bb.x + 0.5f * bb.z, bb.y + 0.5f * bb.w);
            const float larger = fmaxf(bb.z, bb.w);
            lab1 = gt_labels[b * G + g];
            const bool green = (lo <= larger) && (larger <= up);
            gray1 = ((glo <= larger) && (larger < lo)) || ((up < larger) && (larger <= gup));
            i1 = green || gray1;
        }
    }
    // ballot-compaction (single wave; ascending-g order preserved)
    const unsigned long long m0 = __ballot(i0);
    const unsigned long long m1 = __ballot(i1);
    const int c0 = __popcll(m0);
    const unsigned long long below = (1ull << tid) - 1ull;
    if (i0) clist[__popcll(m0 & below)] =
        (unsigned)tid | ((unsigned)lab0 << 8) | (gray0 ? 0x80000000u : 0u);
    if (i1) clist[c0 + __popcll(m1 & below)] =
        (unsigned)(tid + 64) | ((unsigned)lab1 << 8) | (gray1 ? 0x80000000u : 0u);
    const int ncomp = c0 + __popcll(m1);

    // --- branchless 4-chain min-score scan over ALL gts (argmin fallback) ---
#define SC(X, Y) rsqrtf(fmaxf(fabsf(px - (X)) * inv_half, 1.0f) * \
                        fmaxf(fabsf(py - (Y)) * inv_half, 1.0f))
    const float4* ctr2 = (const float4*)ctr;
    float ms0 = 1e30f, ms1 = 1e30f, ms2 = 1e30f, ms3 = 1e30f;
    int   mg0 = 0, mg1 = 0, mg2 = 0, mg3 = 0;
    int g = 0;
    for (; g + 8 <= G; g += 8) {
        const float4 ca = ctr2[(g >> 1) + 0];
        const float4 cb = ctr2[(g >> 1) + 1];
        const float4 cc = ctr2[(g >> 1) + 2];
        const float4 cd = ctr2[(g >> 1) + 3];
        float s;
        s = SC(ca.x, ca.y); if (s < ms0) { ms0 = s; mg0 = g + 0; }
        s = SC(ca.z, ca.w); if (s < ms0) { ms0 = s; mg0 = g + 1; }
        s = SC(cb.x, cb.y); if (s < ms1) { ms1 = s; mg1 = g + 2; }
        s = SC(cb.z, cb.w); if (s < ms1) { ms1 = s; mg1 = g + 3; }
        s = SC(cc.x, cc.y); if (s < ms2) { ms2 = s; mg2 = g + 4; }
        s = SC(cc.z, cc.w); if (s < ms2) { ms2 = s; mg2 = g + 5; }
        s = SC(cd.x, cd.y); if (s < ms3) { ms3 = s; mg3 = g + 6; }
        s = SC(cd.z, cd.w); if (s < ms3) { ms3 = s; mg3 = g + 7; }
    }
    for (; g + 2 <= G; g += 2) {          // tail pairs -> chain 0
        const float4 ca = ctr2[g >> 1];
        float s;
        s = SC(ca.x, ca.y); if (s < ms0) { ms0 = s; mg0 = g; }
        s = SC(ca.z, ca.w); if (s < ms0) { ms0 = s; mg0 = g + 1; }
    }
    if (g < G) {                           // odd tail -> chain 0
        const float2 c = ctr[g];
        const float s = SC(c.x, c.y);
        if (s < ms0) { ms0 = s; mg0 = g; }
    }
    // lexicographic merge == sequential strict-< (first g among float-ties)
    float min_score = ms0; int min_g = mg0;
    if (ms1 < min_score || (ms1 == min_score && mg1 < min_g)) { min_score = ms1; min_g = mg1; }
    if (ms2 < min_score || (ms2 == min_score && mg2 < min_g)) { min_score = ms2; min_g = mg2; }
    if (ms3 < min_score || (ms3 == min_score && mg3 < min_g)) { min_score = ms3; min_g = mg3; }

    // --- heavy loop over compacted gts: hit test, green atomics, gray mask ---
    float* myout = out + ((size_t)b * P + p) * ROWF;
    float best_score = 0.f; int best_g = 0;
    unsigned gm0 = 0u, gm1 = 0u, gm2 = 0u;
    for (int i = 0; i < ncomp; ++i) {
        const unsigned e = clist[i];
        const int gg = (int)(e & 0xFFu);
        const float4 A = boxA[gg];
        const float d1 = px - A.x, d2 = py - A.y, d3 = A.z - px, d4 = A.w - py;
        if (fminf(fminf(d1, d2), fminf(d3, d4)) >= 0.0f) {
            const int label = (int)((e >> 8) & 0x7Fu);
            if (e & 0x80000000u) {               // gray
                if (label < 32)      gm0 |= 1u << label;
                else if (label < 64) gm1 |= 1u << (label - 32);
                else                 gm2 |= 1u << (label - 64);
            } else {                              // green
                const float2 c = ctr[gg];
                const float s = SC(c.x, c.y);
                // zeros landed in kernel A; s>0 so int order == float order
                atomicMax((int*)(myout + label), __float_as_int(s));
                if (s > best_score) { best_score = s; best_g = gg; }
            }
        }
    }
#undef SC

    // own atomics must land before own gray -1 stores (same addresses);
    // waits only on this wave's few atomics -- no bulk-store backlog.
    asm volatile("s_waitcnt vmcnt(0)" ::: "memory");

    // --- gray overrides + reg store (row p touched only by thread p) ---
    unsigned t;
    t = gm0; while (t) { const int c = __ffs(t) - 1; myout[c]      = -1.0f; t &= t - 1u; }
    t = gm1; while (t) { const int c = __ffs(t) - 1; myout[32 + c] = -1.0f; t &= t - 1u; }
    t = gm2; while (t) { const int c = __ffs(t) - 1; myout[64 + c] = -1.0f; t &= t - 1u; }

    const int sel = (best_score > 0.f) ? best_g : min_g;
    const float4 A = boxA[sel];
    *(float4*)(myout + 80) = make_float4((px - A.x) * inv_up, (py - A.y) * inv_up,
                                         (A.z - px) * inv_up, (A.w - py) * inv_up);
}

extern "C" void kernel_launch(void* const* d_in, const int* in_sizes, int n_in,
                              void* d_out, int out_size, void* d_ws, size_t ws_size,
                              hipStream_t stream) {
    const float* gt_bboxes   = (const float*)d_in[0];
    const int*   gt_labels   = (const int*)d_in[1];
    const float* points      = (const float*)d_in[2];
    const float* reg_ranges  = (const float*)d_in[3];
    const float* gray_ranges = (const float*)d_in[4];
    const float* strides     = (const float*)d_in[5];
    float* out = (float*)d_out;

    const int P = in_sizes[5];            // strides has P elements
    const int B = out_size / (P * ROWF);  // out is (B,P,84)
    const int G = in_sizes[1] / B;        // gt_labels is (B,G)  (G<=128 assumed)

    // Kernel A: zero the whole output at streaming-store speed.
    const int n4 = out_size / 4;          // out_size % 4 == 0 (84*P*B)
    lfd_zero_kernel<<<1024, 256, 0, stream>>>((float4*)out, n4);

    // Kernel B: compute + sparse patches (stream-ordered after the fill).
    dim3 grid(P / 64, B);
    dim3 block(64);
    const size_t shmem = (size_t)G * sizeof(float4)               // boxA
                       + (size_t)((G + 1) & ~1) * sizeof(float2)  // ctr
                       + (size_t)G * sizeof(unsigned);            // clist
    lfd_patch_kernel<<<grid, block, shmem, stream>>>(
        gt_bboxes, gt_labels, points, reg_ranges, gray_ranges, strides, out, G, P);
}